// Round 9
// baseline (352.401 us; speedup 1.0000x reference)
//
#include <hip/hip_runtime.h>
#include <math.h>

#define NQ 300
#define NC 42
#define NPROB (NQ * NC)   // 12600
#define K_TOP 100
#define T_DIM 3
#define MH 72
#define MW 128
#define IMG_H 272
#define IMG_W 480
#define ORIG_H 544
#define ORIG_W 960

// out layout (floats): scores[2*100] | labels[2*100] | refs[2*100*4] | masks[2*100*3*544*960]
#define OUT_SCORES 0
#define OUT_LABELS 200
#define OUT_REFS   400
#define OUT_MASKS  1200

#define TILE_LD 132   // 128 + 4 pad: breaks 128-stride LDS bank aliasing
#define NBINS 2048
#define MAXCAND 1024

typedef float f32x4 __attribute__((ext_vector_type(4)));  // native vector: OK for nontemporal builtins

// ---------------- Kernel 1: histogram-select top-k (no serial k-loop) ----------------
// prob = sigmoid(logit) in (0,1): positive f32s compare like their uint bits.
// 1) histogram of (bits>>19); 2) suffix-scan -> boundary bin B (equal values
// share a bin, so bins >= B contain the exact top-100 incl. ties);
// 3) collect candidates; 4) exact rank via key = (bits<<14)|(16383-idx)
// (descending value, ascending index == jax.lax.top_k). Deterministic.
__global__ __launch_bounds__(256) void topk_kernel(
    const float* __restrict__ logits,      // (2, 300, 42)
    const float* __restrict__ ref_points,  // (2, 300, 4)
    float* __restrict__ out,
    int* __restrict__ boxes_ws)            // (2, 100)
{
    __shared__ float          probs[NPROB];      // 50.4 KB
    __shared__ unsigned       hist[NBINS];       // 8 KB
    __shared__ unsigned       chunk[256];
    __shared__ unsigned       cand_pb[MAXCAND];
    __shared__ unsigned short cand_idx[MAXCAND];
    __shared__ int ncand, Bsel;

    const int b   = blockIdx.x;
    const int tid = threadIdx.x;

    for (int i = tid; i < NBINS; i += 256) hist[i] = 0;
    if (tid == 0) ncand = 0;
    __syncthreads();

    for (int i = tid; i < NPROB; i += 256) {
        float x = logits[b * NPROB + i];
        float p = 1.f / (1.f + expf(-x));
        probs[i] = p;
        atomicAdd(&hist[__float_as_uint(p) >> 19], 1u);
    }
    __syncthreads();

    unsigned s = 0;
    #pragma unroll
    for (int k = 0; k < NBINS / 256; ++k) s += hist[tid * (NBINS / 256) + k];
    chunk[tid] = s;
    __syncthreads();

    if (tid == 0) {
        unsigned acc = 0; int B = 0;
        for (int c = 255; c >= 0; --c) {
            if (acc + chunk[c] >= K_TOP) {
                unsigned a2 = acc;
                for (int bin = c * (NBINS / 256) + (NBINS / 256) - 1; bin >= c * (NBINS / 256); --bin) {
                    a2 += hist[bin];
                    if (a2 >= K_TOP) { B = bin; break; }
                }
                break;
            }
            acc += chunk[c];
        }
        Bsel = B;
    }
    __syncthreads();

    const unsigned B = (unsigned)Bsel;
    for (int i = tid; i < NPROB; i += 256) {
        unsigned pb = __float_as_uint(probs[i]);
        if ((pb >> 19) >= B) {
            int pos = atomicAdd(&ncand, 1);
            if (pos < MAXCAND) { cand_pb[pos] = pb; cand_idx[pos] = (unsigned short)i; }
        }
    }
    __syncthreads();

    int n = ncand; if (n > MAXCAND) n = MAXCAND;
    for (int j = tid; j < n; j += 256) {
        unsigned pbj = cand_pb[j]; int ij = cand_idx[j];
        unsigned long long keyj = ((unsigned long long)pbj << 14) | (unsigned)(16383 - ij);
        int rank = 0;
        for (int m = 0; m < n; ++m) {   // same m across lanes -> LDS broadcast
            unsigned long long keym =
                ((unsigned long long)cand_pb[m] << 14) | (unsigned)(16383 - cand_idx[m]);
            rank += (keym > keyj) ? 1 : 0;
        }
        if (rank < K_TOP) {
            int box = ij / NC;
            int lab = ij - box * NC;
            out[OUT_SCORES + b * K_TOP + rank] = __uint_as_float(pbj);
            out[OUT_LABELS + b * K_TOP + rank] = (float)lab;
            boxes_ws[b * K_TOP + rank] = box;
            const float* rp = ref_points + (size_t)(b * NQ + box) * 4;
            float* ro = out + OUT_REFS + (size_t)(b * K_TOP + rank) * 4;
            ro[0] = rp[0]; ro[1] = rp[1]; ro[2] = rp[2]; ro[3] = rp[3];
        }
    }
}

// ---------------- Kernel 2: gather + bilinear x4 + band-threshold + nearest x2 ----------------
// Identical math to R6/R7 (passing, absmax 0.5). ONLY change: the two output
// stores are NONTEMPORAL — the 1.25 GB write-once output was thrashing the
// 4 MiB/XCD L2; streaming stores bypass allocation and go straight to HBM.
__global__ __launch_bounds__(256) void masks_kernel(
    const float* __restrict__ pred_masks,  // (2, 300, 3, 72, 128)
    const int* __restrict__ boxes,         // (2, 100)
    float* __restrict__ out_masks)         // (2, 100, 3, 544, 960) as float
{
    __shared__ float tile[6 * TILE_LD];    // up to 6 mask rows, padded stride

    const int bx = blockIdx.x;             // ((b*100 + q)*3 + t)
    const int by = blockIdx.y;             // 0..16 (16 source rows each)
    const int t  = bx % T_DIM;
    const int q  = (bx / T_DIM) % K_TOP;
    const int b  = bx / (T_DIM * K_TOP);

    const int box = boxes[b * K_TOP + q];
    const float* src = pred_masks + (((size_t)(b * NQ + box)) * T_DIM + t) * (size_t)(MH * MW);

    const int row_lo = (4 * by - 1 > 0) ? (4 * by - 1) : 0;
    const int nelem  = (4 * by + 4 - row_lo + 1) * MW;
    for (int i = threadIdx.x; i < nelem; i += 256) {
        int rr = i >> 7, cc = i & 127;
        tile[rr * TILE_LD + cc] = src[(row_lo + rr) * MW + cc];
    }
    __syncthreads();

    const int tid = threadIdx.x;
    const int r   = tid >> 4;              // 0..15: source row within block
    const int c   = tid & 15;              // 0..15: column-pair phase
    const int sy  = by * 16 + r;

    int   ty  = 2 * sy - 3;
    int   iy0 = ty >> 3;
    float fy  = (float)(ty & 7) * 0.125f;
    if (iy0 < 0) { iy0 = 0; fy = 0.f; }    // edge renorm == weight 1 on row 0
    int   iy1 = iy0 + 1; if (iy1 > MH - 1) iy1 = MH - 1;
    const float* r0 = tile + (iy0 - row_lo) * TILE_LD;
    const float* r1 = tile + (iy1 - row_lo) * TILE_LD;
    const float wy0 = 1.f - fy, wy1 = fy;

    float* dst = out_masks + (size_t)bx * (ORIG_H * ORIG_W) + (size_t)(2 * sy) * ORIG_W;

    for (int it = 0; it < 15; ++it) {
        int p  = c + (it << 4);            // 0..239: source-x pair index
        int tx = 4 * p - 3;
        int ix0 = tx >> 3;
        float fx0 = (float)(tx & 7) * 0.125f;
        int ix1 = ix0 + 1;
        if (ix0 < 0) { ix0 = 0; ix1 = 0; } // p==0: both samples = column 0
        float fx1 = fx0 + 0.25f;

        float a  = fmaf(wy1, r1[ix0], wy0 * r0[ix0]);
        float bb = fmaf(wy1, r1[ix1], wy0 * r0[ix1]);
        float d  = bb - a;
        float v0 = fmaf(fx0, d, a);
        float v1 = fmaf(fx1, d, a);

        float m0 = (v0 > 1e-5f) ? 1.f : ((v0 < -1e-5f) ? 0.f : 0.5f);
        float m1 = (v1 > 1e-5f) ? 1.f : ((v1 < -1e-5f) ? 0.f : 0.5f);

        f32x4 o = { m0, m0, m1, m1 };
        __builtin_nontemporal_store(o, (f32x4*)(dst + 4 * p));            // row 2*sy
        __builtin_nontemporal_store(o, (f32x4*)(dst + 4 * p + ORIG_W));   // row 2*sy+1
    }
}

extern "C" void kernel_launch(void* const* d_in, const int* in_sizes, int n_in,
                              void* d_out, int out_size, void* d_ws, size_t ws_size,
                              hipStream_t stream) {
    const float* pred_logits = (const float*)d_in[0];
    const float* pred_masks  = (const float*)d_in[1];
    const float* ref_points  = (const float*)d_in[2];
    float* out = (float*)d_out;
    int* boxes_ws = (int*)d_ws;

    topk_kernel<<<dim3(2), dim3(256), 0, stream>>>(pred_logits, ref_points, out, boxes_ws);

    dim3 grid2(2 * K_TOP * T_DIM, IMG_H / 16);  // (600, 17)
    masks_kernel<<<grid2, dim3(256), 0, stream>>>(pred_masks, boxes_ws, out + OUT_MASKS);
}

// Round 10
// 296.348 us; speedup vs baseline: 1.1891x; 1.1891x over previous
//
#include <hip/hip_runtime.h>
#include <math.h>

#define NQ 300
#define NC 42
#define NPROB (NQ * NC)   // 12600
#define K_TOP 100
#define T_DIM 3
#define MH 72
#define MW 128
#define IMG_H 272
#define IMG_W 480
#define ORIG_H 544
#define ORIG_W 960

// out layout (floats): scores[2*100] | labels[2*100] | refs[2*100*4] | masks[2*100*3*544*960]
#define OUT_SCORES 0
#define OUT_LABELS 200
#define OUT_REFS   400
#define OUT_MASKS  1200

#define TILE_LD 132   // 128 + 4 pad
#define NBINS 2048
#define MAXCAND 1024

// ---------------- Kernel 1: histogram-select top-k (R7, unchanged) ----------------
__global__ __launch_bounds__(256) void topk_kernel(
    const float* __restrict__ logits,      // (2, 300, 42)
    const float* __restrict__ ref_points,  // (2, 300, 4)
    float* __restrict__ out,
    int* __restrict__ boxes_ws)            // (2, 100)
{
    __shared__ float          probs[NPROB];      // 50.4 KB
    __shared__ unsigned       hist[NBINS];       // 8 KB
    __shared__ unsigned       chunk[256];
    __shared__ unsigned       cand_pb[MAXCAND];
    __shared__ unsigned short cand_idx[MAXCAND];
    __shared__ int ncand, Bsel;

    const int b   = blockIdx.x;
    const int tid = threadIdx.x;

    for (int i = tid; i < NBINS; i += 256) hist[i] = 0;
    if (tid == 0) ncand = 0;
    __syncthreads();

    for (int i = tid; i < NPROB; i += 256) {
        float x = logits[b * NPROB + i];
        float p = 1.f / (1.f + expf(-x));
        probs[i] = p;
        atomicAdd(&hist[__float_as_uint(p) >> 19], 1u);
    }
    __syncthreads();

    unsigned s = 0;
    #pragma unroll
    for (int k = 0; k < NBINS / 256; ++k) s += hist[tid * (NBINS / 256) + k];
    chunk[tid] = s;
    __syncthreads();

    if (tid == 0) {
        unsigned acc = 0; int B = 0;
        for (int c = 255; c >= 0; --c) {
            if (acc + chunk[c] >= K_TOP) {
                unsigned a2 = acc;
                for (int bin = c * (NBINS / 256) + (NBINS / 256) - 1; bin >= c * (NBINS / 256); --bin) {
                    a2 += hist[bin];
                    if (a2 >= K_TOP) { B = bin; break; }
                }
                break;
            }
            acc += chunk[c];
        }
        Bsel = B;
    }
    __syncthreads();

    const unsigned B = (unsigned)Bsel;
    for (int i = tid; i < NPROB; i += 256) {
        unsigned pb = __float_as_uint(probs[i]);
        if ((pb >> 19) >= B) {
            int pos = atomicAdd(&ncand, 1);
            if (pos < MAXCAND) { cand_pb[pos] = pb; cand_idx[pos] = (unsigned short)i; }
        }
    }
    __syncthreads();

    int n = ncand; if (n > MAXCAND) n = MAXCAND;
    for (int j = tid; j < n; j += 256) {
        unsigned pbj = cand_pb[j]; int ij = cand_idx[j];
        unsigned long long keyj = ((unsigned long long)pbj << 14) | (unsigned)(16383 - ij);
        int rank = 0;
        for (int m = 0; m < n; ++m) {   // same m across lanes -> LDS broadcast
            unsigned long long keym =
                ((unsigned long long)cand_pb[m] << 14) | (unsigned)(16383 - cand_idx[m]);
            rank += (keym > keyj) ? 1 : 0;
        }
        if (rank < K_TOP) {
            int box = ij / NC;
            int lab = ij - box * NC;
            out[OUT_SCORES + b * K_TOP + rank] = __uint_as_float(pbj);
            out[OUT_LABELS + b * K_TOP + rank] = (float)lab;
            boxes_ws[b * K_TOP + rank] = box;
            const float* rp = ref_points + (size_t)(b * NQ + box) * 4;
            float* ro = out + OUT_REFS + (size_t)(b * K_TOP + rank) * 4;
            ro[0] = rp[0]; ro[1] = rp[1]; ro[2] = rp[2]; ro[3] = rp[3];
        }
    }
}

// ---------------- Kernel 2: wave-per-row masks (plain stores, fill-like pattern) ----------------
// Same math as R7 (passing, absmax 0.5). Changes vs R7:
//  - nt stores REVERTED to plain float4 stores (R9 showed nt costs +24us).
//  - wave-per-row mapping: wave w owns 4 source rows; for each row its 64
//    lanes write p = lane + 64j (j=0..3), so every store instruction is a
//    1KB contiguous chunk of ONE output row — same pattern as the 6.6 TB/s
//    fill kernel (vs 8 scattered 256B segments before).
//  - y-interp state (iy0, fy, r0, r1, dst) is wave-uniform -> SGPRs.
__global__ __launch_bounds__(256) void masks_kernel(
    const float* __restrict__ pred_masks,  // (2, 300, 3, 72, 128)
    const int* __restrict__ boxes,         // (2, 100)
    float* __restrict__ out_masks)         // (2, 100, 3, 544, 960) as float
{
    __shared__ float tile[6 * TILE_LD];    // up to 6 mask rows, padded stride

    const int bx = blockIdx.x;             // ((b*100 + q)*3 + t)
    const int by = blockIdx.y;             // 0..16 (16 source rows each)
    const int t  = bx % T_DIM;
    const int q  = (bx / T_DIM) % K_TOP;
    const int b  = bx / (T_DIM * K_TOP);

    const int box = boxes[b * K_TOP + q];
    const float* src = pred_masks + (((size_t)(b * NQ + box)) * T_DIM + t) * (size_t)(MH * MW);

    // mask rows touched by source rows [16by, 16by+15]: [max(4by-1,0), 4by+4]
    const int row_lo = (4 * by - 1 > 0) ? (4 * by - 1) : 0;
    const int nelem  = (4 * by + 4 - row_lo + 1) * MW;
    for (int i = threadIdx.x; i < nelem; i += 256) {
        int rr = i >> 7, cc = i & 127;
        tile[rr * TILE_LD + cc] = src[(row_lo + rr) * MW + cc];
    }
    __syncthreads();

    const int tid = threadIdx.x;
    const int w   = tid >> 6;              // wave 0..3
    const int l   = tid & 63;              // lane

    #pragma unroll
    for (int rr = 0; rr < 4; ++rr) {
        const int sy = by * 16 + w * 4 + rr;    // wave-uniform source row

        int   ty  = 2 * sy - 3;
        int   iy0 = ty >> 3;
        float fy  = (float)(ty & 7) * 0.125f;
        if (iy0 < 0) { iy0 = 0; fy = 0.f; }     // edge renorm == weight 1 on row 0
        // iy1 = iy0+1 <= 68 < MH always; staged rows cover [row_lo, 4by+4]
        const float* r0 = tile + (iy0 - row_lo) * TILE_LD;
        const float* r1 = r0 + TILE_LD;
        const float wy0 = 1.f - fy, wy1 = fy;

        float* dst = out_masks + (size_t)bx * (ORIG_H * ORIG_W) + (size_t)(2 * sy) * ORIG_W;

        #pragma unroll
        for (int j = 0; j < 4; ++j) {
            int p = l + (j << 6);               // source-x pair index
            if (j < 3 || p < 240) {             // j<3 is compile-time
                int tx = 4 * p - 3;
                int ix0 = tx >> 3;
                float fx0 = (float)(tx & 7) * 0.125f;
                int ix1 = ix0 + 1;
                if (ix0 < 0) { ix0 = 0; ix1 = 0; }  // p==0: both samples = col 0
                float fx1 = fx0 + 0.25f;

                float a  = fmaf(wy1, r1[ix0], wy0 * r0[ix0]);
                float bb = fmaf(wy1, r1[ix1], wy0 * r0[ix1]);
                float d  = bb - a;
                float v0 = fmaf(fx0, d, a);
                float v1 = fmaf(fx1, d, a);

                float m0 = (v0 > 1e-5f) ? 1.f : ((v0 < -1e-5f) ? 0.f : 0.5f);
                float m1 = (v1 > 1e-5f) ? 1.f : ((v1 < -1e-5f) ? 0.f : 0.5f);

                float4 o = make_float4(m0, m0, m1, m1);
                *(float4*)(dst + 4 * p)          = o;   // row 2*sy   (1KB/wave contiguous)
                *(float4*)(dst + 4 * p + ORIG_W) = o;   // row 2*sy+1 (1KB/wave contiguous)
            }
        }
    }
}

extern "C" void kernel_launch(void* const* d_in, const int* in_sizes, int n_in,
                              void* d_out, int out_size, void* d_ws, size_t ws_size,
                              hipStream_t stream) {
    const float* pred_logits = (const float*)d_in[0];
    const float* pred_masks  = (const float*)d_in[1];
    const float* ref_points  = (const float*)d_in[2];
    float* out = (float*)d_out;
    int* boxes_ws = (int*)d_ws;

    topk_kernel<<<dim3(2), dim3(256), 0, stream>>>(pred_logits, ref_points, out, boxes_ws);

    dim3 grid2(2 * K_TOP * T_DIM, IMG_H / 16);  // (600, 17)
    masks_kernel<<<grid2, dim3(256), 0, stream>>>(pred_masks, boxes_ws, out + OUT_MASKS);
}

// Round 11
// 282.243 us; speedup vs baseline: 1.2486x; 1.0500x over previous
//
#include <hip/hip_runtime.h>
#include <math.h>

#define NQ 300
#define NC 42
#define NPROB (NQ * NC)   // 12600
#define K_TOP 100
#define T_DIM 3
#define MH 72
#define MW 128
#define IMG_H 272
#define IMG_W 480
#define ORIG_H 544
#define ORIG_W 960

// out layout (floats): scores[2*100] | labels[2*100] | refs[2*100*4] | masks[2*100*3*544*960]
#define OUT_SCORES 0
#define OUT_LABELS 200
#define OUT_REFS   400
#define OUT_MASKS  1200

#define TILE_LD 132   // 128 + 4 pad
#define NBINS 2048
#define MAXCAND 1024

#define NCHUNK 17                    // 272/16 row-chunks per tile
#define NTILE  (2 * K_TOP * T_DIM)   // 600
#define NBLK   (NTILE * NCHUNK)      // 10200 (divisible by 8)

// ---------------- Kernel 1: histogram-select top-k (R7, unchanged) ----------------
__global__ __launch_bounds__(256) void topk_kernel(
    const float* __restrict__ logits,      // (2, 300, 42)
    const float* __restrict__ ref_points,  // (2, 300, 4)
    float* __restrict__ out,
    int* __restrict__ boxes_ws)            // (2, 100)
{
    __shared__ float          probs[NPROB];      // 50.4 KB
    __shared__ unsigned       hist[NBINS];       // 8 KB
    __shared__ unsigned       chunk[256];
    __shared__ unsigned       cand_pb[MAXCAND];
    __shared__ unsigned short cand_idx[MAXCAND];
    __shared__ int ncand, Bsel;

    const int b   = blockIdx.x;
    const int tid = threadIdx.x;

    for (int i = tid; i < NBINS; i += 256) hist[i] = 0;
    if (tid == 0) ncand = 0;
    __syncthreads();

    for (int i = tid; i < NPROB; i += 256) {
        float x = logits[b * NPROB + i];
        float p = 1.f / (1.f + expf(-x));
        probs[i] = p;
        atomicAdd(&hist[__float_as_uint(p) >> 19], 1u);
    }
    __syncthreads();

    unsigned s = 0;
    #pragma unroll
    for (int k = 0; k < NBINS / 256; ++k) s += hist[tid * (NBINS / 256) + k];
    chunk[tid] = s;
    __syncthreads();

    if (tid == 0) {
        unsigned acc = 0; int B = 0;
        for (int c = 255; c >= 0; --c) {
            if (acc + chunk[c] >= K_TOP) {
                unsigned a2 = acc;
                for (int bin = c * (NBINS / 256) + (NBINS / 256) - 1; bin >= c * (NBINS / 256); --bin) {
                    a2 += hist[bin];
                    if (a2 >= K_TOP) { B = bin; break; }
                }
                break;
            }
            acc += chunk[c];
        }
        Bsel = B;
    }
    __syncthreads();

    const unsigned B = (unsigned)Bsel;
    for (int i = tid; i < NPROB; i += 256) {
        unsigned pb = __float_as_uint(probs[i]);
        if ((pb >> 19) >= B) {
            int pos = atomicAdd(&ncand, 1);
            if (pos < MAXCAND) { cand_pb[pos] = pb; cand_idx[pos] = (unsigned short)i; }
        }
    }
    __syncthreads();

    int n = ncand; if (n > MAXCAND) n = MAXCAND;
    for (int j = tid; j < n; j += 256) {
        unsigned pbj = cand_pb[j]; int ij = cand_idx[j];
        unsigned long long keyj = ((unsigned long long)pbj << 14) | (unsigned)(16383 - ij);
        int rank = 0;
        for (int m = 0; m < n; ++m) {   // same m across lanes -> LDS broadcast
            unsigned long long keym =
                ((unsigned long long)cand_pb[m] << 14) | (unsigned)(16383 - cand_idx[m]);
            rank += (keym > keyj) ? 1 : 0;
        }
        if (rank < K_TOP) {
            int box = ij / NC;
            int lab = ij - box * NC;
            out[OUT_SCORES + b * K_TOP + rank] = __uint_as_float(pbj);
            out[OUT_LABELS + b * K_TOP + rank] = (float)lab;
            boxes_ws[b * K_TOP + rank] = box;
            const float* rp = ref_points + (size_t)(b * NQ + box) * 4;
            float* ro = out + OUT_REFS + (size_t)(b * K_TOP + rank) * 4;
            ro[0] = rp[0]; ro[1] = rp[1]; ro[2] = rp[2]; ro[3] = rp[3];
        }
    }
}

// ---------------- Kernel 2: wave-per-row masks + XCD-linear write streams ----------------
// Math and store shape identical to R10 (passing, 296us). ONLY change: block->
// work mapping. 1D grid, xcd = bid&7 owns a CONTIGUOUS slab of the output:
//   chunk = (bid&7)*1275 + (bid>>3)   in [0,10200)
//   tile  = chunk/17, by = chunk%17
// Consecutive chunks are address-adjacent (tile region = 17 x 120KB contiguous),
// so each XCD's resident blocks form one dense sliding write window (~30MB)
// instead of ~600 windows strided 2.09MB apart -> L2 evicts in address order,
// HBM row-buffer hits (the fill kernel's pattern, 6.6 TB/s).
__global__ __launch_bounds__(256) void masks_kernel(
    const float* __restrict__ pred_masks,  // (2, 300, 3, 72, 128)
    const int* __restrict__ boxes,         // (2, 100)
    float* __restrict__ out_masks)         // (2, 100, 3, 544, 960) as float
{
    __shared__ float tile[6 * TILE_LD];    // up to 6 mask rows, padded stride

    const int bid   = blockIdx.x;
    const int chunk = (bid & 7) * (NBLK / 8) + (bid >> 3);
    const int bx    = chunk / NCHUNK;      // tile id: ((b*100 + q)*3 + t)
    const int by    = chunk - bx * NCHUNK; // row-chunk 0..16

    const int t  = bx % T_DIM;
    const int q  = (bx / T_DIM) % K_TOP;
    const int b  = bx / (T_DIM * K_TOP);

    const int box = boxes[b * K_TOP + q];
    const float* src = pred_masks + (((size_t)(b * NQ + box)) * T_DIM + t) * (size_t)(MH * MW);

    // mask rows touched by source rows [16by, 16by+15]: [max(4by-1,0), 4by+4]
    const int row_lo = (4 * by - 1 > 0) ? (4 * by - 1) : 0;
    const int nelem  = (4 * by + 4 - row_lo + 1) * MW;
    for (int i = threadIdx.x; i < nelem; i += 256) {
        int rr = i >> 7, cc = i & 127;
        tile[rr * TILE_LD + cc] = src[(row_lo + rr) * MW + cc];
    }
    __syncthreads();

    const int tid = threadIdx.x;
    const int w   = tid >> 6;              // wave 0..3
    const int l   = tid & 63;              // lane

    #pragma unroll
    for (int rr = 0; rr < 4; ++rr) {
        const int sy = by * 16 + w * 4 + rr;    // wave-uniform source row

        int   ty  = 2 * sy - 3;
        int   iy0 = ty >> 3;
        float fy  = (float)(ty & 7) * 0.125f;
        if (iy0 < 0) { iy0 = 0; fy = 0.f; }     // edge renorm == weight 1 on row 0
        const float* r0 = tile + (iy0 - row_lo) * TILE_LD;
        const float* r1 = r0 + TILE_LD;
        const float wy0 = 1.f - fy, wy1 = fy;

        float* dst = out_masks + (size_t)bx * (ORIG_H * ORIG_W) + (size_t)(2 * sy) * ORIG_W;

        #pragma unroll
        for (int j = 0; j < 4; ++j) {
            int p = l + (j << 6);               // source-x pair index
            if (j < 3 || p < 240) {             // j<3 is compile-time
                int tx = 4 * p - 3;
                int ix0 = tx >> 3;
                float fx0 = (float)(tx & 7) * 0.125f;
                int ix1 = ix0 + 1;
                if (ix0 < 0) { ix0 = 0; ix1 = 0; }  // p==0: both samples = col 0
                float fx1 = fx0 + 0.25f;

                float a  = fmaf(wy1, r1[ix0], wy0 * r0[ix0]);
                float bb = fmaf(wy1, r1[ix1], wy0 * r0[ix1]);
                float d  = bb - a;
                float v0 = fmaf(fx0, d, a);
                float v1 = fmaf(fx1, d, a);

                float m0 = (v0 > 1e-5f) ? 1.f : ((v0 < -1e-5f) ? 0.f : 0.5f);
                float m1 = (v1 > 1e-5f) ? 1.f : ((v1 < -1e-5f) ? 0.f : 0.5f);

                float4 o = make_float4(m0, m0, m1, m1);
                *(float4*)(dst + 4 * p)          = o;   // row 2*sy   (1KB/wave contiguous)
                *(float4*)(dst + 4 * p + ORIG_W) = o;   // row 2*sy+1 (1KB/wave contiguous)
            }
        }
    }
}

extern "C" void kernel_launch(void* const* d_in, const int* in_sizes, int n_in,
                              void* d_out, int out_size, void* d_ws, size_t ws_size,
                              hipStream_t stream) {
    const float* pred_logits = (const float*)d_in[0];
    const float* pred_masks  = (const float*)d_in[1];
    const float* ref_points  = (const float*)d_in[2];
    float* out = (float*)d_out;
    int* boxes_ws = (int*)d_ws;

    topk_kernel<<<dim3(2), dim3(256), 0, stream>>>(pred_logits, ref_points, out, boxes_ws);

    masks_kernel<<<dim3(NBLK), dim3(256), 0, stream>>>(pred_masks, boxes_ws, out + OUT_MASKS);
}

// Round 12
// 278.993 us; speedup vs baseline: 1.2631x; 1.0117x over previous
//
#include <hip/hip_runtime.h>
#include <math.h>

#define NQ 300
#define NC 42
#define NPROB (NQ * NC)   // 12600
#define K_TOP 100
#define T_DIM 3
#define MH 72
#define MW 128
#define IMG_H 272
#define IMG_W 480
#define ORIG_H 544
#define ORIG_W 960

// out layout (floats): scores[2*100] | labels[2*100] | refs[2*100*4] | masks[2*100*3*544*960]
#define OUT_SCORES 0
#define OUT_LABELS 200
#define OUT_REFS   400
#define OUT_MASKS  1200

#define TILE_LD 132   // 128 + 4 pad
#define NBINS 2048
#define MAXCAND 1024

#define NCHUNK 17                    // 272/16 row-chunks per tile
#define NTILE  (2 * K_TOP * T_DIM)   // 600
#define NBLK   (NTILE * NCHUNK)      // 10200 (divisible by 8)

// ---------------- Kernel 1: histogram-select top-k (R7, unchanged) ----------------
__global__ __launch_bounds__(256) void topk_kernel(
    const float* __restrict__ logits,      // (2, 300, 42)
    const float* __restrict__ ref_points,  // (2, 300, 4)
    float* __restrict__ out,
    int* __restrict__ boxes_ws)            // (2, 100)
{
    __shared__ float          probs[NPROB];      // 50.4 KB
    __shared__ unsigned       hist[NBINS];       // 8 KB
    __shared__ unsigned       chunk[256];
    __shared__ unsigned       cand_pb[MAXCAND];
    __shared__ unsigned short cand_idx[MAXCAND];
    __shared__ int ncand, Bsel;

    const int b   = blockIdx.x;
    const int tid = threadIdx.x;

    for (int i = tid; i < NBINS; i += 256) hist[i] = 0;
    if (tid == 0) ncand = 0;
    __syncthreads();

    for (int i = tid; i < NPROB; i += 256) {
        float x = logits[b * NPROB + i];
        float p = 1.f / (1.f + expf(-x));
        probs[i] = p;
        atomicAdd(&hist[__float_as_uint(p) >> 19], 1u);
    }
    __syncthreads();

    unsigned s = 0;
    #pragma unroll
    for (int k = 0; k < NBINS / 256; ++k) s += hist[tid * (NBINS / 256) + k];
    chunk[tid] = s;
    __syncthreads();

    if (tid == 0) {
        unsigned acc = 0; int B = 0;
        for (int c = 255; c >= 0; --c) {
            if (acc + chunk[c] >= K_TOP) {
                unsigned a2 = acc;
                for (int bin = c * (NBINS / 256) + (NBINS / 256) - 1; bin >= c * (NBINS / 256); --bin) {
                    a2 += hist[bin];
                    if (a2 >= K_TOP) { B = bin; break; }
                }
                break;
            }
            acc += chunk[c];
        }
        Bsel = B;
    }
    __syncthreads();

    const unsigned B = (unsigned)Bsel;
    for (int i = tid; i < NPROB; i += 256) {
        unsigned pb = __float_as_uint(probs[i]);
        if ((pb >> 19) >= B) {
            int pos = atomicAdd(&ncand, 1);
            if (pos < MAXCAND) { cand_pb[pos] = pb; cand_idx[pos] = (unsigned short)i; }
        }
    }
    __syncthreads();

    int n = ncand; if (n > MAXCAND) n = MAXCAND;
    for (int j = tid; j < n; j += 256) {
        unsigned pbj = cand_pb[j]; int ij = cand_idx[j];
        unsigned long long keyj = ((unsigned long long)pbj << 14) | (unsigned)(16383 - ij);
        int rank = 0;
        for (int m = 0; m < n; ++m) {   // same m across lanes -> LDS broadcast
            unsigned long long keym =
                ((unsigned long long)cand_pb[m] << 14) | (unsigned)(16383 - cand_idx[m]);
            rank += (keym > keyj) ? 1 : 0;
        }
        if (rank < K_TOP) {
            int box = ij / NC;
            int lab = ij - box * NC;
            out[OUT_SCORES + b * K_TOP + rank] = __uint_as_float(pbj);
            out[OUT_LABELS + b * K_TOP + rank] = (float)lab;
            boxes_ws[b * K_TOP + rank] = box;
            const float* rp = ref_points + (size_t)(b * NQ + box) * 4;
            float* ro = out + OUT_REFS + (size_t)(b * K_TOP + rank) * 4;
            ro[0] = rp[0]; ro[1] = rp[1]; ro[2] = rp[2]; ro[3] = rp[3];
        }
    }
}

// ---------------- Kernel 2: wave-per-row masks, SEQUENTIAL store stream ----------------
// Identical math & mapping to R11 (282us). ONLY change: store ORDER.
// R11 issued A0,B0,A1,B1,... (alternating rows 2sy/2sy+1, +-3840B jumps).
// Rows 2sy and 2sy+1 are ADJACENT in memory, so computing o[0..3] into
// registers and issuing A0..A3 then B0..B3 makes each rr-iteration one
// strictly-sequential 7.68KB burst; the wave's whole rr-loop is a monotonic
// 30.7KB sweep (rows 8w..8w+7 of the 32-row chunk) — the fill kernel's
// address pattern at DRAM-page granularity.
__global__ __launch_bounds__(256) void masks_kernel(
    const float* __restrict__ pred_masks,  // (2, 300, 3, 72, 128)
    const int* __restrict__ boxes,         // (2, 100)
    float* __restrict__ out_masks)         // (2, 100, 3, 544, 960) as float
{
    __shared__ float tile[6 * TILE_LD];    // up to 6 mask rows, padded stride

    const int bid   = blockIdx.x;
    const int chunk = (bid & 7) * (NBLK / 8) + (bid >> 3);   // XCD-linear slabs (R11, +14us)
    const int bx    = chunk / NCHUNK;      // tile id: ((b*100 + q)*3 + t)
    const int by    = chunk - bx * NCHUNK; // row-chunk 0..16

    const int t  = bx % T_DIM;
    const int q  = (bx / T_DIM) % K_TOP;
    const int b  = bx / (T_DIM * K_TOP);

    const int box = boxes[b * K_TOP + q];
    const float* src = pred_masks + (((size_t)(b * NQ + box)) * T_DIM + t) * (size_t)(MH * MW);

    // mask rows touched by source rows [16by, 16by+15]: [max(4by-1,0), 4by+4]
    const int row_lo = (4 * by - 1 > 0) ? (4 * by - 1) : 0;
    const int nelem  = (4 * by + 4 - row_lo + 1) * MW;
    for (int i = threadIdx.x; i < nelem; i += 256) {
        int rr = i >> 7, cc = i & 127;
        tile[rr * TILE_LD + cc] = src[(row_lo + rr) * MW + cc];
    }
    __syncthreads();

    const int tid = threadIdx.x;
    const int w   = tid >> 6;              // wave 0..3
    const int l   = tid & 63;              // lane

    #pragma unroll
    for (int rr = 0; rr < 4; ++rr) {
        const int sy = by * 16 + w * 4 + rr;    // wave-uniform source row

        int   ty  = 2 * sy - 3;
        int   iy0 = ty >> 3;
        float fy  = (float)(ty & 7) * 0.125f;
        if (iy0 < 0) { iy0 = 0; fy = 0.f; }     // edge renorm == weight 1 on row 0
        const float* r0 = tile + (iy0 - row_lo) * TILE_LD;
        const float* r1 = r0 + TILE_LD;
        const float wy0 = 1.f - fy, wy1 = fy;

        float* dstA = out_masks + (size_t)bx * (ORIG_H * ORIG_W) + (size_t)(2 * sy) * ORIG_W;
        float* dstB = dstA + ORIG_W;

        float4 o[4];
        #pragma unroll
        for (int j = 0; j < 4; ++j) {
            int p = l + (j << 6);               // source-x pair index
            if (j < 3 || p < 240) {             // j<3 is compile-time
                int tx = 4 * p - 3;
                int ix0 = tx >> 3;
                float fx0 = (float)(tx & 7) * 0.125f;
                int ix1 = ix0 + 1;
                if (ix0 < 0) { ix0 = 0; ix1 = 0; }  // p==0: both samples = col 0
                float fx1 = fx0 + 0.25f;

                float a  = fmaf(wy1, r1[ix0], wy0 * r0[ix0]);
                float bb = fmaf(wy1, r1[ix1], wy0 * r0[ix1]);
                float d  = bb - a;
                float v0 = fmaf(fx0, d, a);
                float v1 = fmaf(fx1, d, a);

                float m0 = (v0 > 1e-5f) ? 1.f : ((v0 < -1e-5f) ? 0.f : 0.5f);
                float m1 = (v1 > 1e-5f) ? 1.f : ((v1 < -1e-5f) ? 0.f : 0.5f);
                o[j] = make_float4(m0, m0, m1, m1);
            }
        }
        #pragma unroll
        for (int j = 0; j < 4; ++j) {           // row 2*sy: sequential 3840B burst
            int p = l + (j << 6);
            if (j < 3 || p < 240) *(float4*)(dstA + 4 * p) = o[j];
        }
        #pragma unroll
        for (int j = 0; j < 4; ++j) {           // row 2*sy+1: next 3840B, contiguous
            int p = l + (j << 6);
            if (j < 3 || p < 240) *(float4*)(dstB + 4 * p) = o[j];
        }
    }
}

extern "C" void kernel_launch(void* const* d_in, const int* in_sizes, int n_in,
                              void* d_out, int out_size, void* d_ws, size_t ws_size,
                              hipStream_t stream) {
    const float* pred_logits = (const float*)d_in[0];
    const float* pred_masks  = (const float*)d_in[1];
    const float* ref_points  = (const float*)d_in[2];
    float* out = (float*)d_out;
    int* boxes_ws = (int*)d_ws;

    topk_kernel<<<dim3(2), dim3(256), 0, stream>>>(pred_logits, ref_points, out, boxes_ws);

    masks_kernel<<<dim3(NBLK), dim3(256), 0, stream>>>(pred_masks, boxes_ws, out + OUT_MASKS);
}